// Round 9
// baseline (85.258 us; speedup 1.0000x reference)
//
#include <hip/hip_runtime.h>
#include <stdint.h>

#define NUM_IN   2048
#define NUM_OUT  1024
#define NINT     1023
#define NLEAF    1024
#define BATCH    4096
#define NPAD     1024

typedef __bf16 bf16x8 __attribute__((ext_vector_type(8)));
typedef float  f32x4  __attribute__((ext_vector_type(4)));

typedef const __attribute__((address_space(1))) void* as1cvp;
typedef __attribute__((address_space(3)))       void* as3vp;

__device__ __forceinline__ void gload16(const void* g, void* l) {
  __builtin_amdgcn_global_load_lds((as1cvp)g, (as3vp)l, 16, 0, 0);
}

__device__ __forceinline__ unsigned short f2bf(float f) {
  unsigned u = __builtin_bit_cast(unsigned, f);
  u += 0x7fffu + ((u >> 16) & 1u);   // RNE
  return (unsigned short)(u >> 16);
}

// ---------------- fused conversions: x->bf16 | W->bf16(pad) | leaf->leaf^T bf16 ----
// grid partition: [0,8192) cvt_x, [8192,10240) cvt_w, [10240,11264) leafT 32x32 tiles
__global__ __launch_bounds__(256) void prep_k(
    const float* __restrict__ x, const float* __restrict__ W,
    const float* __restrict__ leaf,
    unsigned short* __restrict__ xb, unsigned short* __restrict__ wb,
    unsigned short* __restrict__ lt)
{
  __shared__ float tile[32][33];
  const int b = blockIdx.x, tid = threadIdx.x;
  if (b < 8192) {                      // x: 4096*2048/4 = 2M float4 groups
    int e = b * 256 + tid;
    float4 v = ((const float4*)x)[e];
    ushort4 o; o.x = f2bf(v.x); o.y = f2bf(v.y); o.z = f2bf(v.z); o.w = f2bf(v.w);
    ((ushort4*)xb)[e] = o;
  } else if (b < 10240) {              // W: 1024*2048/4 = 512K groups, row 1023 zeroed
    int e = (b - 8192) * 256 + tid;
    int row = e >> 9;
    ushort4 o;
    if (row < NINT) {
      float4 v = ((const float4*)W)[e];
      o.x = f2bf(v.x); o.y = f2bf(v.y); o.z = f2bf(v.z); o.w = f2bf(v.w);
    } else { o.x = 0; o.y = 0; o.z = 0; o.w = 0; }
    ((ushort4*)wb)[e] = o;
  } else {                             // leaf^T: 32x32 grid of 32x32 tiles
    int t = b - 10240;
    int bx = t & 31, by = t >> 5;
    int xx = tid & 31, y0 = tid >> 5;  // 32 x 8
    #pragma unroll
    for (int i = 0; i < 4; ++i) {
      int y = y0 + i * 8;
      tile[y][xx] = leaf[(size_t)(by * 32 + y) * NUM_OUT + bx * 32 + xx];
    }
    __syncthreads();
    #pragma unroll
    for (int i = 0; i < 4; ++i) {
      int y = y0 + i * 8;
      lt[(size_t)(bx * 32 + y) * NLEAF + by * 32 + xx] = f2bf(tile[xx][y]);
    }
  }
}

// ---------------- bf16 MFMA GEMM, B^T form: C[M,N] = A[M,K] * B[N,K]^T ----------------
// m97 geometry: BM=BN=128 BK=64, 256 threads = 4 waves (2x2), wave tile 64x64,
// acc[4][4] (16 MFMA per 8 ds_read_b128). XOR-swizzled LDS (pre-swizzled global
// source, swizzled ds_read) + double-buffered prefetch, 1 barrier/K-step.
template<bool SIG>
__global__ __launch_bounds__(256, 2) void gemm_bt_k(
    const unsigned short* __restrict__ A,
    const unsigned short* __restrict__ B,
    float* __restrict__ C,
    const float* __restrict__ bias,
    int M, int N, int K, int nbias)
{
  __shared__ alignas(16) unsigned short lA[2][128 * 64];
  __shared__ alignas(16) unsigned short lB[2][128 * 64];
  const int tid = threadIdx.x;
  const int wid = tid >> 6, lane = tid & 63;
  const int wm = wid >> 1, wn = wid & 1;
  const int bm = blockIdx.x * 128;
  const int bn = blockIdx.y * 128;

  f32x4 acc[4][4];
  #pragma unroll
  for (int i = 0; i < 4; ++i)
    #pragma unroll
    for (int j = 0; j < 4; ++j)
      #pragma unroll
      for (int r = 0; r < 4; ++r) acc[i][j][r] = 0.f;

  const unsigned short* Ab = A + (size_t)bm * K;
  const unsigned short* Bb = B + (size_t)bn * K;
  const int rlA  = lane >> 3;                 // row within 8-row chunk (= row&7)
  const int ksrc = ((lane & 7) ^ rlA) * 8;    // inverse-swizzled source k-offset
  // LDS physical (row r, 16B-chunk pc) holds logical chunk pc^(r&7).

  auto STAGE = [&](int b, int k0) {
    #pragma unroll
    for (int c = 0; c < 4; ++c) {             // 16 chunks of 8 rows, 4 per wave
      int ch = wid * 4 + c;
      int r  = ch * 8 + rlA;
      gload16(Ab + (size_t)r * K + k0 + ksrc, &lA[b][ch * 512]);
      gload16(Bb + (size_t)r * K + k0 + ksrc, &lB[b][ch * 512]);
    }
  };

  STAGE(0, 0);
  int cur = 0;
  for (int k0 = 0; k0 < K; k0 += 64) {
    __syncthreads();                  // drains vmcnt: buf[cur] staged; prev compute done
    if (k0 + 64 < K) STAGE(cur ^ 1, k0 + 64);   // prefetch next under this compute

    const int swz = lane & 7;         // fragment row&7 (rows are 16*j + (lane&15))
    #pragma unroll
    for (int s = 0; s < 2; ++s) {
      const int cl = s * 4 + (lane >> 4);        // logical 16B chunk within row
      const int ko = (cl ^ swz) * 8;             // physical elem offset (swizzled)
      bf16x8 af[4], bfr[4];
      #pragma unroll
      for (int mi = 0; mi < 4; ++mi)
        af[mi] = *(const bf16x8*)&lA[cur][(wm * 64 + mi * 16 + (lane & 15)) * 64 + ko];
      #pragma unroll
      for (int ni = 0; ni < 4; ++ni)
        bfr[ni] = *(const bf16x8*)&lB[cur][(wn * 64 + ni * 16 + (lane & 15)) * 64 + ko];
      #pragma unroll
      for (int mi = 0; mi < 4; ++mi)
        #pragma unroll
        for (int ni = 0; ni < 4; ++ni)
          acc[mi][ni] = __builtin_amdgcn_mfma_f32_16x16x32_bf16(af[mi], bfr[ni], acc[mi][ni], 0, 0, 0);
    }
    cur ^= 1;
  }

  // C/D layout (verified): col = lane&15, row = (lane>>4)*4 + reg
  #pragma unroll
  for (int ni = 0; ni < 4; ++ni) {
    const int col = bn + wn * 64 + ni * 16 + (lane & 15);
    float bv = 0.f;
    if (SIG) bv = (col < nbias) ? bias[col] : 0.f;
    #pragma unroll
    for (int mi = 0; mi < 4; ++mi) {
      const int row0 = bm + wm * 64 + mi * 16 + (lane >> 4) * 4;
      #pragma unroll
      for (int r = 0; r < 4; ++r) {
        float v = acc[mi][ni][r];
        if (SIG) { v += bv; v = 1.f / (1.f + __expf(-v)); }
        C[(size_t)(row0 + r) * N + col] = v;
      }
    }
  }
}

// ---------------- per-sample p + idx ----------------
// one block (256 thr) per sample; p hierarchical from f32 V; idx walk on wave 0
// with exact fp32 logit recompute when |v-0.5|<0.04 (bf16 GEMM error ~0.004 in v-space)
__global__ __launch_bounds__(256) void p_idx_k(
    const float* __restrict__ V, const float* __restrict__ x,
    const float* __restrict__ W, const float* __restrict__ bias,
    unsigned short* __restrict__ P, float* __restrict__ idx_out)
{
  __shared__ alignas(16) float vrow[1024];
  const int i = blockIdx.x, tid = threadIdx.x;
  ((float4*)vrow)[tid] = ((const float4*)(V + (size_t)i * NPAD))[tid];
  __syncthreads();

  // p for leaves [tid*4, tid*4+4): shared ancestor prefix over depths 0..7
  const int L0 = tid * 4;
  float pp = 1.f;
  #pragma unroll
  for (int d = 0; d < 8; ++d) {
    int node = ((1 << d) - 1) + (L0 >> (10 - d));
    float v = vrow[node];
    pp *= ((L0 >> (9 - d)) & 1) ? v : (1.f - v);
  }
  float v8  = vrow[255 + (L0 >> 2)];
  float v9a = vrow[511 + (L0 >> 1)];
  float v9b = vrow[512 + (L0 >> 1)];
  float qa = pp * (1.f - v8), qb = pp * v8;
  ushort4 o;
  o.x = f2bf(qa * (1.f - v9a));
  o.y = f2bf(qa * v9a);
  o.z = f2bf(qb * (1.f - v9b));
  o.w = f2bf(qb * v9b);
  ((ushort4*)(P + (size_t)i * NLEAF))[tid] = o;

  if (tid < 64) {                      // wave 0: decision walk
    const int lane = tid;
    int idx = 0;
    #pragma unroll
    for (int d = 0; d < 10; ++d) {
      int node = ((1 << d) - 1) + idx;
      float v = vrow[node];            // wave-uniform
      int bit;
      if (__builtin_fabsf(v - 0.5f) < 0.04f) {   // borderline: exact fp32 logit
        const float* xr = x + (size_t)i * NUM_IN;
        const float* wr = W + (size_t)node * NUM_IN;
        float s = 0.f;
        #pragma unroll
        for (int t = 0; t < 8; ++t) {
          float4 xv = ((const float4*)xr)[lane + t * 64];
          float4 wv = ((const float4*)wr)[lane + t * 64];
          s += xv.x * wv.x + xv.y * wv.y + xv.z * wv.z + xv.w * wv.w;
        }
        #pragma unroll
        for (int m = 32; m > 0; m >>= 1) s += __shfl_xor(s, m);
        s += bias[node];
        bit = (s >= 0.f) ? 1 : 0;
      } else {
        bit = (v >= 0.5f) ? 1 : 0;
      }
      idx = 2 * idx + bit;
    }
    if (lane == 0) idx_out[i] = (float)idx;
  }
}

extern "C" void kernel_launch(void* const* d_in, const int* in_sizes, int n_in,
                              void* d_out, int out_size, void* d_ws, size_t ws_size,
                              hipStream_t stream) {
  const float* x    = (const float*)d_in[0];   // 4096 x 2048
  const float* W    = (const float*)d_in[1];   // 1023 x 2048
  const float* b    = (const float*)d_in[2];   // 1023
  const float* leaf = (const float*)d_in[3];   // 1024 x 1024
  float* out = (float*)d_out;                  // 4096x1024 f32, then 4096 idx-as-f32

  // workspace layout (bytes), total ~48 MB
  char* ws = (char*)d_ws;
  unsigned short* xb = (unsigned short*)(ws + 0);          // 16 MB  x bf16
  unsigned short* wb = (unsigned short*)(ws + 16777216);   //  4 MB  W bf16 (padded 1024 rows)
  float*          Vf = (float*)        (ws + 20971520);    // 16 MB  V f32 (stride 1024)
  unsigned short* Pb = (unsigned short*)(ws + 37748736);   //  8 MB  p bf16
  unsigned short* LT = (unsigned short*)(ws + 46137344);   //  2 MB  leaf^T bf16

  prep_k<<<11264, 256, 0, stream>>>(x, W, leaf, xb, wb, LT);

  // V = sigmoid(x @ W^T + b): M=4096 N=1024(padded) K=2048
  gemm_bt_k<true><<<dim3(BATCH / 128, NPAD / 128), 256, 0, stream>>>(
      xb, wb, Vf, b, BATCH, NPAD, NUM_IN, NINT);

  p_idx_k<<<BATCH, 256, 0, stream>>>(Vf, x, W, b, Pb, out + (size_t)BATCH * NUM_OUT);

  // out = p @ leaf_dist: M=4096 N=1024 K=1024
  gemm_bt_k<false><<<dim3(BATCH / 128, NUM_OUT / 128), 256, 0, stream>>>(
      Pb, LT, out, nullptr, BATCH, NUM_OUT, NLEAF, 0);
}

// Round 10
// 70.652 us; speedup vs baseline: 1.2067x; 1.2067x over previous
//
#include <hip/hip_runtime.h>
#include <stdint.h>

#define NUM_IN   2048
#define NUM_OUT  1024
#define NINT     1023
#define NLEAF    1024
#define BATCH    4096
#define NPAD     1024

typedef __bf16 bf16x8 __attribute__((ext_vector_type(8)));
typedef float  f32x4  __attribute__((ext_vector_type(4)));

typedef const __attribute__((address_space(1))) void* as1cvp;
typedef __attribute__((address_space(3)))       void* as3vp;

__device__ __forceinline__ void gload16(const void* g, void* l) {
  __builtin_amdgcn_global_load_lds((as1cvp)g, (as3vp)l, 16, 0, 0);
}

__device__ __forceinline__ unsigned short f2bf(float f) {
  unsigned u = __builtin_bit_cast(unsigned, f);
  u += 0x7fffu + ((u >> 16) & 1u);   // RNE
  return (unsigned short)(u >> 16);
}

// ---------------- fused conversions: x->bf16 | W->bf16(pad) | leaf->leaf^T bf16 ----
// grid partition: [0,8192) cvt_x, [8192,10240) cvt_w, [10240,11264) leafT 32x32 tiles
__global__ __launch_bounds__(256) void prep_k(
    const float* __restrict__ x, const float* __restrict__ W,
    const float* __restrict__ leaf,
    unsigned short* __restrict__ xb, unsigned short* __restrict__ wb,
    unsigned short* __restrict__ lt)
{
  __shared__ float tile[32][33];
  const int b = blockIdx.x, tid = threadIdx.x;
  if (b < 8192) {                      // x: 4096*2048/4 = 2M float4 groups
    int e = b * 256 + tid;
    float4 v = ((const float4*)x)[e];
    ushort4 o; o.x = f2bf(v.x); o.y = f2bf(v.y); o.z = f2bf(v.z); o.w = f2bf(v.w);
    ((ushort4*)xb)[e] = o;
  } else if (b < 10240) {              // W: 1024*2048/4 = 512K groups, row 1023 zeroed
    int e = (b - 8192) * 256 + tid;
    int row = e >> 9;
    ushort4 o;
    if (row < NINT) {
      float4 v = ((const float4*)W)[e];
      o.x = f2bf(v.x); o.y = f2bf(v.y); o.z = f2bf(v.z); o.w = f2bf(v.w);
    } else { o.x = 0; o.y = 0; o.z = 0; o.w = 0; }
    ((ushort4*)wb)[e] = o;
  } else {                             // leaf^T: 32x32 grid of 32x32 tiles
    int t = b - 10240;
    int bx = t & 31, by = t >> 5;
    int xx = tid & 31, y0 = tid >> 5;  // 32 x 8
    #pragma unroll
    for (int i = 0; i < 4; ++i) {
      int y = y0 + i * 8;
      tile[y][xx] = leaf[(size_t)(by * 32 + y) * NUM_OUT + bx * 32 + xx];
    }
    __syncthreads();
    #pragma unroll
    for (int i = 0; i < 4; ++i) {
      int y = y0 + i * 8;
      lt[(size_t)(bx * 32 + y) * NLEAF + by * 32 + xx] = f2bf(tile[xx][y]);
    }
  }
}

// ---------------- bf16 MFMA GEMM, B^T form: C[M,N] = A[M,K] * B[N,K]^T ----------------
// Occupancy-first geometry: BM=BN=64 BK=64, 256 threads = 4 waves (2x2),
// wave tile 32x32, acc[2][2]. 1024 blocks = 4 blocks/CU = 16 waves/CU.
// XOR-swizzled LDS (pre-swizzled global source + swizzled ds_read, verified
// conflict-free R9) + double-buffered prefetch, 1 barrier/K-step.
template<bool SIG>
__global__ __launch_bounds__(256, 4) void gemm_bt_k(
    const unsigned short* __restrict__ A,
    const unsigned short* __restrict__ B,
    float* __restrict__ C,
    const float* __restrict__ bias,
    int M, int N, int K, int nbias)
{
  __shared__ alignas(16) unsigned short lA[2][64 * 64];
  __shared__ alignas(16) unsigned short lB[2][64 * 64];
  const int tid = threadIdx.x;
  const int wid = tid >> 6, lane = tid & 63;
  const int wm = wid >> 1, wn = wid & 1;
  const int bm = blockIdx.x * 64;
  const int bn = blockIdx.y * 64;

  f32x4 acc[2][2];
  #pragma unroll
  for (int i = 0; i < 2; ++i)
    #pragma unroll
    for (int j = 0; j < 2; ++j)
      #pragma unroll
      for (int r = 0; r < 4; ++r) acc[i][j][r] = 0.f;

  const unsigned short* Ab = A + (size_t)bm * K;
  const unsigned short* Bb = B + (size_t)bn * K;
  const int rlA  = lane >> 3;                 // row within 8-row chunk (= row&7)
  const int ksrc = ((lane & 7) ^ rlA) * 8;    // inverse-swizzled source k-offset
  // LDS physical (row r, 16B-chunk pc) holds logical chunk pc^(r&7).

  auto STAGE = [&](int b, int k0) {
    #pragma unroll
    for (int c = 0; c < 2; ++c) {             // 8 chunks of 8 rows each, 2 per wave
      int ch = wid * 2 + c;
      int r  = ch * 8 + rlA;
      gload16(Ab + (size_t)r * K + k0 + ksrc, &lA[b][ch * 512]);
      gload16(Bb + (size_t)r * K + k0 + ksrc, &lB[b][ch * 512]);
    }
  };

  STAGE(0, 0);
  int cur = 0;
  for (int k0 = 0; k0 < K; k0 += 64) {
    __syncthreads();                  // buf[cur] staged; prev compute done
    if (k0 + 64 < K) STAGE(cur ^ 1, k0 + 64);   // prefetch next under this compute

    const int swz = lane & 7;         // fragment row&7 (rows are 16*i + (lane&15))
    #pragma unroll
    for (int s = 0; s < 2; ++s) {
      const int cl = s * 4 + (lane >> 4);        // logical 16B chunk within row
      const int ko = (cl ^ swz) * 8;             // physical elem offset (swizzled)
      bf16x8 af[2], bfr[2];
      #pragma unroll
      for (int mi = 0; mi < 2; ++mi)
        af[mi] = *(const bf16x8*)&lA[cur][(wm * 32 + mi * 16 + (lane & 15)) * 64 + ko];
      #pragma unroll
      for (int ni = 0; ni < 2; ++ni)
        bfr[ni] = *(const bf16x8*)&lB[cur][(wn * 32 + ni * 16 + (lane & 15)) * 64 + ko];
      #pragma unroll
      for (int mi = 0; mi < 2; ++mi)
        #pragma unroll
        for (int ni = 0; ni < 2; ++ni)
          acc[mi][ni] = __builtin_amdgcn_mfma_f32_16x16x32_bf16(af[mi], bfr[ni], acc[mi][ni], 0, 0, 0);
    }
    cur ^= 1;
  }

  // C/D layout (verified): col = lane&15, row = (lane>>4)*4 + reg
  #pragma unroll
  for (int ni = 0; ni < 2; ++ni) {
    const int col = bn + wn * 32 + ni * 16 + (lane & 15);
    float bv = 0.f;
    if (SIG) bv = (col < nbias) ? bias[col] : 0.f;
    #pragma unroll
    for (int mi = 0; mi < 2; ++mi) {
      const int row0 = bm + wm * 32 + mi * 16 + (lane >> 4) * 4;
      #pragma unroll
      for (int r = 0; r < 4; ++r) {
        float v = acc[mi][ni][r];
        if (SIG) { v += bv; v = 1.f / (1.f + __expf(-v)); }
        C[(size_t)(row0 + r) * N + col] = v;
      }
    }
  }
}

// ---------------- per-sample p + idx ----------------
// one block (256 thr) per sample; p hierarchical from f32 V; idx walk on wave 0
// with exact fp32 logit recompute when |v-0.5|<0.04 (bf16 GEMM error ~0.004 in v-space)
__global__ __launch_bounds__(256) void p_idx_k(
    const float* __restrict__ V, const float* __restrict__ x,
    const float* __restrict__ W, const float* __restrict__ bias,
    unsigned short* __restrict__ P, float* __restrict__ idx_out)
{
  __shared__ alignas(16) float vrow[1024];
  const int i = blockIdx.x, tid = threadIdx.x;
  ((float4*)vrow)[tid] = ((const float4*)(V + (size_t)i * NPAD))[tid];
  __syncthreads();

  // p for leaves [tid*4, tid*4+4): shared ancestor prefix over depths 0..7
  const int L0 = tid * 4;
  float pp = 1.f;
  #pragma unroll
  for (int d = 0; d < 8; ++d) {
    int node = ((1 << d) - 1) + (L0 >> (10 - d));
    float v = vrow[node];
    pp *= ((L0 >> (9 - d)) & 1) ? v : (1.f - v);
  }
  float v8  = vrow[255 + (L0 >> 2)];
  float v9a = vrow[511 + (L0 >> 1)];
  float v9b = vrow[512 + (L0 >> 1)];
  float qa = pp * (1.f - v8), qb = pp * v8;
  ushort4 o;
  o.x = f2bf(qa * (1.f - v9a));
  o.y = f2bf(qa * v9a);
  o.z = f2bf(qb * (1.f - v9b));
  o.w = f2bf(qb * v9b);
  ((ushort4*)(P + (size_t)i * NLEAF))[tid] = o;

  if (tid < 64) {                      // wave 0: decision walk
    const int lane = tid;
    int idx = 0;
    #pragma unroll
    for (int d = 0; d < 10; ++d) {
      int node = ((1 << d) - 1) + idx;
      float v = vrow[node];            // wave-uniform
      int bit;
      if (__builtin_fabsf(v - 0.5f) < 0.04f) {   // borderline: exact fp32 logit
        const float* xr = x + (size_t)i * NUM_IN;
        const float* wr = W + (size_t)node * NUM_IN;
        float s = 0.f;
        #pragma unroll
        for (int t = 0; t < 8; ++t) {
          float4 xv = ((const float4*)xr)[lane + t * 64];
          float4 wv = ((const float4*)wr)[lane + t * 64];
          s += xv.x * wv.x + xv.y * wv.y + xv.z * wv.z + xv.w * wv.w;
        }
        #pragma unroll
        for (int m = 32; m > 0; m >>= 1) s += __shfl_xor(s, m);
        s += bias[node];
        bit = (s >= 0.f) ? 1 : 0;
      } else {
        bit = (v >= 0.5f) ? 1 : 0;
      }
      idx = 2 * idx + bit;
    }
    if (lane == 0) idx_out[i] = (float)idx;
  }
}

extern "C" void kernel_launch(void* const* d_in, const int* in_sizes, int n_in,
                              void* d_out, int out_size, void* d_ws, size_t ws_size,
                              hipStream_t stream) {
  const float* x    = (const float*)d_in[0];   // 4096 x 2048
  const float* W    = (const float*)d_in[1];   // 1023 x 2048
  const float* b    = (const float*)d_in[2];   // 1023
  const float* leaf = (const float*)d_in[3];   // 1024 x 1024
  float* out = (float*)d_out;                  // 4096x1024 f32, then 4096 idx-as-f32

  // workspace layout (bytes), total ~48 MB
  char* ws = (char*)d_ws;
  unsigned short* xb = (unsigned short*)(ws + 0);          // 16 MB  x bf16
  unsigned short* wb = (unsigned short*)(ws + 16777216);   //  4 MB  W bf16 (padded 1024 rows)
  float*          Vf = (float*)        (ws + 20971520);    // 16 MB  V f32 (stride 1024)
  unsigned short* Pb = (unsigned short*)(ws + 37748736);   //  8 MB  p bf16
  unsigned short* LT = (unsigned short*)(ws + 46137344);   //  2 MB  leaf^T bf16

  prep_k<<<11264, 256, 0, stream>>>(x, W, leaf, xb, wb, LT);

  // V = sigmoid(x @ W^T + b): M=4096 N=1024(padded) K=2048
  gemm_bt_k<true><<<dim3(BATCH / 64, NPAD / 64), 256, 0, stream>>>(
      xb, wb, Vf, b, BATCH, NPAD, NUM_IN, NINT);

  p_idx_k<<<BATCH, 256, 0, stream>>>(Vf, x, W, b, Pb, out + (size_t)BATCH * NUM_OUT);

  // out = p @ leaf_dist: M=4096 N=1024 K=1024
  gemm_bt_k<false><<<dim3(BATCH / 64, NUM_OUT / 64), 256, 0, stream>>>(
      Pb, LT, out, nullptr, BATCH, NUM_OUT, NLEAF, 0);
}